// Round 1
// baseline (423.240 us; speedup 1.0000x reference)
//
#include <hip/hip_runtime.h>
#include <hip/hip_bf16.h>

#define TD 128   // feature dim, fixed by problem
#define WS 136   // padded W-LDS row stride in bf16 (272 B: 16B-aligned, bank-uniform for b128)
#define SC_T 8   // triples per scoring block
#define NXCD 8   // XCDs on MI355X; degx has NXCD replicas

typedef __attribute__((ext_vector_type(8))) short bf16x8;   // 8 bf16 = 4 VGPR (MFMA A/B frag)
typedef __attribute__((ext_vector_type(4))) float f32x4;    // MFMA C/D frag

static __device__ __forceinline__ unsigned short f2bf(float f) {
    unsigned int u = __float_as_uint(f);
    u += 0x7fffu + ((u >> 16) & 1u);   // round-to-nearest-even
    return (unsigned short)(u >> 16);
}
static __device__ __forceinline__ float bf2f(unsigned short h) {
    return __uint_as_float((unsigned int)h << 16);
}

// ---------------- pass 1: degree + within-bucket rank, XCD-local atomics ----------------
// Device-scope atomicAdd write-throughs ~32B/op past L2 (56MB WRITE_SIZE, 67us). Instead:
// per-XCD replica counters + workgroup-scope atomics. Atomics execute at the XCD's own L2
// (no sc1 bypass); replica x is only ever touched from XCD x, so the L2 RMW is race-free.
// rank packs (local_rank<<3)|xcd; k_merge turns replica counts into per-XCD base offsets.
__global__ __launch_bounds__(256) void k_rank(const int* __restrict__ ei, int* __restrict__ degx,
                                              int* __restrict__ rank, int E_, int N_) {
    unsigned xcc;
    asm volatile("s_getreg_b32 %0, hwreg(HW_REG_XCC_ID)" : "=s"(xcc));
    xcc &= (NXCD - 1);
    int e = blockIdx.x * 256 + threadIdx.x;
    if (e < E_) {
        int d = ei[E_ + e];   // dst = row 1
        int lr = __hip_atomic_fetch_add(&degx[(size_t)xcc * N_ + d], 1,
                                        __ATOMIC_RELAXED, __HIP_MEMORY_SCOPE_WORKGROUP);
        rank[e] = (lr << 3) | (int)xcc;
    }
}

// per node: exclusive scan of the 8 replica counts (in place -> per-XCD slot base),
// deg = total, dinv = deg^-1/2 (folds old k_dinv). All 8 streams coalesced (stride N).
__global__ __launch_bounds__(256) void k_merge(int* __restrict__ degx, int* __restrict__ deg,
                                               float* __restrict__ dinv, int n) {
    int i = blockIdx.x * 256 + threadIdx.x;
    if (i >= n) return;
    int run = 0;
#pragma unroll
    for (int x = 0; x < NXCD; ++x) {
        size_t idx = (size_t)x * n + i;
        int c = degx[idx];
        degx[idx] = run;
        run += c;
    }
    deg[i] = run;
    dinv[i] = (run > 0) ? 1.0f / sqrtf((float)run) : 0.0f;
}

// ---------------- exclusive scan (3-kernel hierarchical) ----------------
__global__ __launch_bounds__(256) void k_scan1(const int* __restrict__ deg, int* __restrict__ rowptr,
                                               int* __restrict__ bsums, int n) {
    __shared__ int wsum[4];
    int t = threadIdx.x;
    int base = blockIdx.x * 1024 + t * 4;
    int a0 = 0, a1 = 0, a2 = 0, a3 = 0;
    if (base + 3 < n) {
        int4 v = *(const int4*)(deg + base);
        a0 = v.x; a1 = v.y; a2 = v.z; a3 = v.w;
    } else {
        if (base     < n) a0 = deg[base];
        if (base + 1 < n) a1 = deg[base + 1];
        if (base + 2 < n) a2 = deg[base + 2];
        if (base + 3 < n) a3 = deg[base + 3];
    }
    int s1 = a0 + a1, s2 = s1 + a2, tot = s2 + a3;
    int lane = t & 63, wv = t >> 6;
    int x = tot;
#pragma unroll
    for (int off = 1; off < 64; off <<= 1) {
        int y = __shfl_up(x, off);
        if (lane >= off) x += y;
    }
    if (lane == 63) wsum[wv] = x;
    __syncthreads();
    int woff = 0;
    for (int w = 0; w < wv; ++w) woff += wsum[w];
    int excl = woff + x - tot;
    if (base     < n) rowptr[base]     = excl;
    if (base + 1 < n) rowptr[base + 1] = excl + a0;
    if (base + 2 < n) rowptr[base + 2] = excl + s1;
    if (base + 3 < n) rowptr[base + 3] = excl + s2;
    if (t == 255) bsums[blockIdx.x] = woff + x;   // block total
}

// parallel single-block scan of block sums (nb <= 1024)
__global__ __launch_bounds__(256) void k_scan2(int* __restrict__ bsums, int nb, int* __restrict__ rowptrN) {
    __shared__ int wsum[4];
    int t = threadIdx.x;
    int base = t * 4;
    int a0 = (base     < nb) ? bsums[base]     : 0;
    int a1 = (base + 1 < nb) ? bsums[base + 1] : 0;
    int a2 = (base + 2 < nb) ? bsums[base + 2] : 0;
    int a3 = (base + 3 < nb) ? bsums[base + 3] : 0;
    int s1 = a0 + a1, s2 = s1 + a2, tot = s2 + a3;
    int lane = t & 63, wv = t >> 6;
    int x = tot;
#pragma unroll
    for (int off = 1; off < 64; off <<= 1) {
        int y = __shfl_up(x, off);
        if (lane >= off) x += y;
    }
    if (lane == 63) wsum[wv] = x;
    __syncthreads();
    int woff = 0;
    for (int w = 0; w < wv; ++w) woff += wsum[w];
    int excl = woff + x - tot;
    if (base     < nb) bsums[base]     = excl;
    if (base + 1 < nb) bsums[base + 1] = excl + a0;
    if (base + 2 < nb) bsums[base + 2] = excl + s1;
    if (base + 3 < nb) bsums[base + 3] = excl + s2;
    if (t == 255) *rowptrN = woff + x;   // grand total = E
}

__global__ __launch_bounds__(256) void k_scan3(int* __restrict__ rowptr, const int* __restrict__ bsums, int n) {
    int i = blockIdx.x * 256 + threadIdx.x;
    if (i < n) rowptr[i] += bsums[i >> 10];
}

// ---------------- pass 2: atomic-free placement ----------------
__global__ __launch_bounds__(256) void k_place(const int* __restrict__ ei, const int* __restrict__ rowptr,
                                               const int* __restrict__ rank, const int* __restrict__ degx,
                                               int* __restrict__ esrc, int E_, int N_) {
    int e = blockIdx.x * 256 + threadIdx.x;
    if (e < E_) {
        int s = ei[e];
        int d = ei[E_ + e];
        int r = rank[e];
        int x = r & (NXCD - 1);
        int lr = r >> 3;
        esrc[rowptr[d] + degx[(size_t)x * N_ + d] + lr] = s;
    }
}

// ---------------- W transpose + hi/lo bf16 split ----------------
__global__ __launch_bounds__(256) void k_wsplit(const float* __restrict__ W1, const float* __restrict__ W2,
                                                unsigned short* __restrict__ Wt) {
    int i = blockIdx.x * 256 + threadIdx.x;   // 0 .. 2*16384-1
    int w = i >> 14;
    int idx = i & 16383;          // = k*128 + n  (coalesced read)
    int k = idx >> 7, n = idx & 127;
    float x = (w ? W2 : W1)[idx];
    unsigned short h = f2bf(x);
    unsigned short l = f2bf(x - bf2f(h));
    size_t base = (size_t)w * 32768;
    Wt[base + n * 128 + k] = h;
    Wt[base + 16384 + n * 128 + k] = l;
}

// ---------------- MFMA GEMM v5: W hi+lo staged to LDS once per block ----------------
// out[r][c] = bf16(scale[r] * sum_k X[r][k]*W[k][c]); f32-equiv precision via bf16 hi/lo split
// (A*B ~= Ah*Bh + Al*Bh + Ah*Bl). W lives in LDS (68KB padded, stride 136 = 16B-aligned +
// bank-uniform for b128), staged once per block; inner loop uses ds_read_b128. A-frags direct
// from global into registers. C stored straight to global. One __syncthreads total. 2 blocks/CU.
__global__ __launch_bounds__(256, 2) void k_gemm(const float* __restrict__ X,
                                                 const unsigned short* __restrict__ Wth,
                                                 const unsigned short* __restrict__ Wtl,
                                                 const float* __restrict__ scale,
                                                 unsigned short* __restrict__ out,
                                                 int nrows) {
    __shared__ __align__(16) unsigned short Wl[2][128 * WS];   // 68 KB (hi, lo)
    const int t = threadIdx.x;
    const int w = t >> 6;
    const int lane = t & 63;
    const int l15 = lane & 15;
    const int quad = lane >> 4;
    const int rbase = blockIdx.x * 64 + w * 16;   // wave's 16-row tile
    const int arow = rbase + l15;                 // this lane's A row
    const bool avalid = arow < nrows;

    // A: 8 float4 loads, issue immediately (independent of staging)
    float4 xa[4][2];
#pragma unroll
    for (int kc = 0; kc < 4; ++kc) {
        const float* src = X + (size_t)arow * TD + kc * 32 + quad * 8;
        xa[kc][0] = avalid ? *(const float4*)src       : make_float4(0.f, 0.f, 0.f, 0.f);
        xa[kc][1] = avalid ? *(const float4*)(src + 4) : make_float4(0.f, 0.f, 0.f, 0.f);
    }

    // stage W hi+lo -> padded LDS: 2048 uint4 per plane, 8 per thread
    {
        const uint4* gh = (const uint4*)Wth;
        const uint4* gl = (const uint4*)Wtl;
#pragma unroll
        for (int it = 0; it < 8; ++it) {
            int idx = t + it * 256;            // 0..2047
            int n = idx >> 4, kg = idx & 15;   // row n, k-group kg (8 bf16 each)
            uint4 vh = gh[idx];
            uint4 vl = gl[idx];
            *(uint4*)&Wl[0][n * WS + kg * 8] = vh;
            *(uint4*)&Wl[1][n * WS + kg * 8] = vl;
        }
    }

    // convert A to bf16 hi/lo fragments while staging is in flight
    bf16x8 ah[4], al[4];
#pragma unroll
    for (int kc = 0; kc < 4; ++kc) {
#pragma unroll
        for (int j = 0; j < 8; ++j) {
            float v = (j < 4) ? ((const float*)&xa[kc][0])[j] : ((const float*)&xa[kc][1])[j - 4];
            unsigned short h = f2bf(v);
            ah[kc][j] = (short)h;
            al[kc][j] = (short)f2bf(v - bf2f(h));
        }
    }
    __syncthreads();

    f32x4 acc[8];
#pragma unroll
    for (int b = 0; b < 8; ++b) acc[b] = (f32x4){0.f, 0.f, 0.f, 0.f};

#pragma unroll
    for (int kc = 0; kc < 4; ++kc) {
        const int koff = kc * 32 + quad * 8;
#pragma unroll
        for (int b = 0; b < 8; ++b) {
            const int boff = (b * 16 + l15) * WS + koff;
            bf16x8 bh = *(const bf16x8*)&Wl[0][boff];
            bf16x8 bl = *(const bf16x8*)&Wl[1][boff];
            acc[b] = __builtin_amdgcn_mfma_f32_16x16x32_bf16(ah[kc], bh, acc[b], 0, 0, 0);
            acc[b] = __builtin_amdgcn_mfma_f32_16x16x32_bf16(al[kc], bh, acc[b], 0, 0, 0);
            acc[b] = __builtin_amdgcn_mfma_f32_16x16x32_bf16(ah[kc], bl, acc[b], 0, 0, 0);
        }
    }

    // epilogue: C/D layout col=lane&15, row=quad*4+reg -> scale + direct bf16 global stores
    {
        int grow = rbase + quad * 4;              // multiple of 4; nrows % 4 == 0
        if (grow < nrows) {
            float4 s4 = *(const float4*)&scale[grow];
#pragma unroll
            for (int b = 0; b < 8; ++b) {
                int col = b * 16 + l15;
                out[(size_t)(grow + 0) * TD + col] = f2bf(acc[b][0] * s4.x);
                out[(size_t)(grow + 1) * TD + col] = f2bf(acc[b][1] * s4.y);
                out[(size_t)(grow + 2) * TD + col] = f2bf(acc[b][2] * s4.z);
                out[(size_t)(grow + 3) * TD + col] = f2bf(acc[b][3] * s4.w);
            }
        }
    }
}

// ---------------- CSR aggregation: bf16 gather, f64 accumulate (order-invariant), f32 out ----------------
__global__ __launch_bounds__(256) void k_agg(const unsigned short* __restrict__ hs, const int* __restrict__ rowptr,
                                             const int* __restrict__ esrc, const float* __restrict__ dinv,
                                             const float* __restrict__ bias, float* __restrict__ out,
                                             int n, int relu) {
    int node = blockIdx.x * 16 + (threadIdx.x >> 4);
    int lane = threadIdx.x & 15;
    if (node >= n) return;
    int s = rowptr[node], e = rowptr[node + 1];
    const uint4* h16 = (const uint4*)hs;
    double a0 = 0, a1 = 0, a2 = 0, a3 = 0, a4 = 0, a5 = 0, a6 = 0, a7 = 0;
    int i = s;
    for (; i + 2 <= e; i += 2) {
        uint4 u = h16[(size_t)esrc[i] * 16 + lane];
        uint4 v = h16[(size_t)esrc[i + 1] * 16 + lane];
        a0 += (double)__uint_as_float(u.x << 16); a1 += (double)__uint_as_float(u.x & 0xffff0000u);
        a2 += (double)__uint_as_float(u.y << 16); a3 += (double)__uint_as_float(u.y & 0xffff0000u);
        a4 += (double)__uint_as_float(u.z << 16); a5 += (double)__uint_as_float(u.z & 0xffff0000u);
        a6 += (double)__uint_as_float(u.w << 16); a7 += (double)__uint_as_float(u.w & 0xffff0000u);
        a0 += (double)__uint_as_float(v.x << 16); a1 += (double)__uint_as_float(v.x & 0xffff0000u);
        a2 += (double)__uint_as_float(v.y << 16); a3 += (double)__uint_as_float(v.y & 0xffff0000u);
        a4 += (double)__uint_as_float(v.z << 16); a5 += (double)__uint_as_float(v.z & 0xffff0000u);
        a6 += (double)__uint_as_float(v.w << 16); a7 += (double)__uint_as_float(v.w & 0xffff0000u);
    }
    if (i < e) {
        uint4 u = h16[(size_t)esrc[i] * 16 + lane];
        a0 += (double)__uint_as_float(u.x << 16); a1 += (double)__uint_as_float(u.x & 0xffff0000u);
        a2 += (double)__uint_as_float(u.y << 16); a3 += (double)__uint_as_float(u.y & 0xffff0000u);
        a4 += (double)__uint_as_float(u.z << 16); a5 += (double)__uint_as_float(u.z & 0xffff0000u);
        a6 += (double)__uint_as_float(u.w << 16); a7 += (double)__uint_as_float(u.w & 0xffff0000u);
    }
    double di = (double)dinv[node];
    float4 b0 = ((const float4*)bias)[lane * 2];
    float4 b1 = ((const float4*)bias)[lane * 2 + 1];
    float o0 = (float)(di * a0 + (double)b0.x);
    float o1 = (float)(di * a1 + (double)b0.y);
    float o2 = (float)(di * a2 + (double)b0.z);
    float o3 = (float)(di * a3 + (double)b0.w);
    float o4 = (float)(di * a4 + (double)b1.x);
    float o5 = (float)(di * a5 + (double)b1.y);
    float o6 = (float)(di * a6 + (double)b1.z);
    float o7 = (float)(di * a7 + (double)b1.w);
    if (relu) {
        o0 = fmaxf(o0, 0.f); o1 = fmaxf(o1, 0.f); o2 = fmaxf(o2, 0.f); o3 = fmaxf(o3, 0.f);
        o4 = fmaxf(o4, 0.f); o5 = fmaxf(o5, 0.f); o6 = fmaxf(o6, 0.f); o7 = fmaxf(o7, 0.f);
    }
    ((float4*)out)[(size_t)node * 32 + lane * 2]     = make_float4(o0, o1, o2, o3);
    ((float4*)out)[(size_t)node * 32 + lane * 2 + 1] = make_float4(o4, o5, o6, o7);
}

// ---------------- relation bucketing: block-aggregated histograms (16 global atomics/block) ----------------
__global__ __launch_bounds__(256) void k_rcnt(const int* __restrict__ rel, int* __restrict__ rcount, int es) {
    __shared__ int lh[16];
    int t = threadIdx.x;
    if (t < 16) lh[t] = 0;
    __syncthreads();
#pragma unroll
    for (int i = 0; i < 4; ++i) {
        int e = blockIdx.x * 1024 + i * 256 + t;
        if (e < es) atomicAdd(&lh[rel[e]], 1);
    }
    __syncthreads();
    if (t < 16 && lh[t]) atomicAdd(&rcount[t], lh[t]);
}

__global__ void k_roff(const int* __restrict__ rcount, int* __restrict__ roff,
                       int* __restrict__ chunkoff, int nr) {
    if (threadIdx.x == 0 && blockIdx.x == 0) {
        int run = 0, crun = 0;
        for (int r = 0; r < nr; ++r) {
            roff[r] = run; chunkoff[r] = crun;
            run += rcount[r]; crun += (rcount[r] + SC_T - 1) / SC_T;
        }
        roff[nr] = run; chunkoff[nr] = crun;
    }
}

__global__ __launch_bounds__(256) void k_bucket(const int* __restrict__ rel, int* __restrict__ cursor,
                                                int* __restrict__ eidx, int es) {
    __shared__ int lh[16];
    __shared__ int lbase[16];
    int t = threadIdx.x;
    if (t < 16) lh[t] = 0;
    __syncthreads();
    int r[4], lr[4];
#pragma unroll
    for (int i = 0; i < 4; ++i) {
        int e = blockIdx.x * 1024 + i * 256 + t;
        if (e < es) {
            r[i] = rel[e];
            lr[i] = atomicAdd(&lh[r[i]], 1);   // LDS atomic: intra-block rank
        } else r[i] = -1;
    }
    __syncthreads();
    if (t < 16) lbase[t] = lh[t] ? atomicAdd(&cursor[t], lh[t]) : 0;   // reserve range
    __syncthreads();
#pragma unroll
    for (int i = 0; i < 4; ++i)
        if (r[i] >= 0) eidx[lbase[r[i]] + lr[i]] = blockIdx.x * 1024 + i * 256 + t;
}

// ---------------- batched scoring: SC_T triples of ONE relation per block, W[r] staged once ----------------
__global__ __launch_bounds__(256) void k_score_r(const float* __restrict__ z, const float* __restrict__ relW,
                                                 const int* __restrict__ eidx, const int* __restrict__ head,
                                                 const int* __restrict__ tail, const int* __restrict__ roff,
                                                 const int* __restrict__ chunkoff, float* __restrict__ out,
                                                 int R_) {
    __shared__ __align__(16) float Wl[TD * TD];      // 64 KB
    __shared__ __align__(16) float zhL[SC_T * TD];   // 4 KB
    __shared__ __align__(16) float ztL[SC_T * TD];   // 4 KB
    __shared__ int eids[SC_T];
    __shared__ int co[17], ro[17];
    __shared__ float red[4][SC_T];
    const int t = threadIdx.x;
    const int b = blockIdx.x;
    if (t < 17 && t <= R_) { co[t] = chunkoff[t]; ro[t] = roff[t]; }
    __syncthreads();
    int r = 0;
    while (r < R_ && co[r + 1] <= b) ++r;
    if (r >= R_) return;                       // uniform: all threads exit together
    const int base = ro[r] + (b - co[r]) * SC_T;
    const int nt = min(SC_T, ro[r + 1] - base);
    if (t < SC_T) eids[t] = (t < nt) ? eidx[base + t] : -1;
    __syncthreads();
    {   // stage zh/zt: 256 float4, 1 per thread
        int tt = t >> 5, c4 = t & 31;
        float4 vh = make_float4(0.f, 0.f, 0.f, 0.f), vt = vh;
        int e = eids[tt];
        if (e >= 0) {
            vh = ((const float4*)(z + (size_t)head[e] * TD))[c4];
            vt = ((const float4*)(z + (size_t)tail[e] * TD))[c4];
        }
        ((float4*)(zhL + tt * TD))[c4] = vh;
        ((float4*)(ztL + tt * TD))[c4] = vt;
    }
    {   // stage W[r]: 4096 float4
        const float4* W4 = (const float4*)(relW + (size_t)r * TD * TD);
        float4* Wl4 = (float4*)Wl;
#pragma unroll
        for (int i = 0; i < 16; ++i) Wl4[t + i * 256] = W4[t + i * 256];
    }
    __syncthreads();

    const int c  = (t & 31) * 4;    // cols c..c+3
    const int i0 = (t >> 5) * 16;   // 16-row i segment
    float4 acc[SC_T];
#pragma unroll
    for (int u = 0; u < SC_T; ++u) acc[u] = make_float4(0.f, 0.f, 0.f, 0.f);
#pragma unroll 4
    for (int i = i0; i < i0 + 16; ++i) {
        float4 wv = *(const float4*)&Wl[i * TD + c];
#pragma unroll
        for (int u = 0; u < SC_T; ++u) {
            float h = zhL[u * TD + i];
            acc[u].x = fmaf(h, wv.x, acc[u].x);
            acc[u].y = fmaf(h, wv.y, acc[u].y);
            acc[u].z = fmaf(h, wv.z, acc[u].z);
            acc[u].w = fmaf(h, wv.w, acc[u].w);
        }
    }
    float pth[SC_T];
#pragma unroll
    for (int u = 0; u < SC_T; ++u) {
        float4 z4 = *(const float4*)&ztL[u * TD + c];
        pth[u] = acc[u].x * z4.x + acc[u].y * z4.y + acc[u].z * z4.z + acc[u].w * z4.w;
    }
#pragma unroll
    for (int off = 32; off > 0; off >>= 1)
#pragma unroll
        for (int u = 0; u < SC_T; ++u) pth[u] += __shfl_down(pth[u], off);
    if ((t & 63) == 0) {
        int wv = t >> 6;
#pragma unroll
        for (int u = 0; u < SC_T; ++u) red[wv][u] = pth[u];
    }
    __syncthreads();
    if (t < SC_T) {
        int e = eids[t];
        if (e >= 0) out[e] = red[0][t] + red[1][t] + red[2][t] + red[3][t];
    }
}

extern "C" void kernel_launch(void* const* d_in, const int* in_sizes, int n_in,
                              void* d_out, int out_size, void* d_ws, size_t ws_size,
                              hipStream_t stream) {
    const float* x0   = (const float*)d_in[0];
    const float* W1   = (const float*)d_in[1];
    const float* b1   = (const float*)d_in[2];
    const float* W2   = (const float*)d_in[3];
    const float* b2   = (const float*)d_in[4];
    const float* relW = (const float*)d_in[5];
    const int*   ei   = (const int*)d_in[6];
    const int*   rel  = (const int*)d_in[7];
    const int*   head = (const int*)d_in[8];
    const int*   tail = (const int*)d_in[9];
    float* outp = (float*)d_out;

    const int N_  = in_sizes[0] / TD;
    const int E_  = in_sizes[6] / 2;
    const int ES_ = in_sizes[7];
    const int R_  = in_sizes[5] / (TD * TD);
    const int nb  = (N_ + 1023) / 1024;
    const int ntiles64 = (N_ + 63) / 64;

    char* p = (char*)d_ws;
    auto alloc = [&](size_t bytes) { char* r = p; p += (bytes + 255) & ~(size_t)255; return r; };
    int*            deg    = (int*)           alloc((size_t)N_ * 4);
    int*            degx   = (int*)           alloc((size_t)NXCD * N_ * 4);   // per-XCD replicas
    float*          dinv   = (float*)         alloc((size_t)N_ * 4);
    int*            rowptr = (int*)           alloc(((size_t)N_ + 1) * 4);
    int*            bsums  = (int*)           alloc((size_t)nb * 4);
    int*            esrc   = (int*)           alloc((size_t)E_ * 4);
    unsigned short* Wt     = (unsigned short*)alloc((size_t)4 * 16384 * 2);   // W1h,W1l,W2h,W2l
    int*            rcount = (int*)           alloc((size_t)R_ * 4);
    int*            roff   = (int*)           alloc(((size_t)R_ + 1) * 4);
    int*            chkoff = (int*)           alloc(((size_t)R_ + 1) * 4);
    int*            cursor = (int*)           alloc((size_t)R_ * 4);
    int*            eidx   = (int*)           alloc((size_t)ES_ * 4);
    unsigned short* bufA   = (unsigned short*)alloc((size_t)N_ * TD * 2);     // bf16 h-scaled
    float*          bufB   = (float*)         alloc((size_t)N_ * TD * 4);     // f32 conv out
    int*            rank   = (int*)bufA;   // alias: dead before first k_gemm writes bufA (E*4 <= N*TD*2)

    hipMemsetAsync(degx, 0, (size_t)NXCD * N_ * 4, stream);
    hipMemsetAsync(rcount, 0, (size_t)R_ * 4, stream);
    k_rank  <<<(E_ + 255) / 256, 256, 0, stream>>>(ei, degx, rank, E_, N_);
    k_merge <<<(N_ + 255) / 256, 256, 0, stream>>>(degx, deg, dinv, N_);
    k_scan1 <<<nb, 256, 0, stream>>>(deg, rowptr, bsums, N_);
    k_scan2 <<<1, 256, 0, stream>>>(bsums, nb, rowptr + N_);
    k_scan3 <<<(N_ + 255) / 256, 256, 0, stream>>>(rowptr, bsums, N_);
    k_place <<<(E_ + 255) / 256, 256, 0, stream>>>(ei, rowptr, rank, degx, esrc, E_, N_);
    k_wsplit<<<128, 256, 0, stream>>>(W1, W2, Wt);

    // relation bucketing for scoring (block-aggregated atomics)
    k_rcnt  <<<(ES_ + 1023) / 1024, 256, 0, stream>>>(rel, rcount, ES_);
    k_roff  <<<1, 64, 0, stream>>>(rcount, roff, chkoff, R_);
    hipMemcpyAsync(cursor, roff, (size_t)R_ * 4, hipMemcpyDeviceToDevice, stream);
    k_bucket<<<(ES_ + 1023) / 1024, 256, 0, stream>>>(rel, cursor, eidx, ES_);

    // conv1: bufA = bf16(dinv * (x0 @ W1)); bufB = relu(dinv*agg(bufA) + b1)
    k_gemm<<<ntiles64, 256, 0, stream>>>(x0, Wt, Wt + 16384, dinv, bufA, N_);
    k_agg <<<(N_ + 15) / 16, 256, 0, stream>>>(bufA, rowptr, esrc, dinv, b1, bufB, N_, 1);
    // conv2: bufA = bf16(dinv * (bufB @ W2)); bufB = dinv*agg(bufA) + b2  (= z)
    k_gemm<<<ntiles64, 256, 0, stream>>>(bufB, Wt + 32768, Wt + 49152, dinv, bufA, N_);
    k_agg <<<(N_ + 15) / 16, 256, 0, stream>>>(bufA, rowptr, esrc, dinv, b2, bufB, N_, 0);

    // scoring: blocks = chunks (upper bound ES/SC_T + R); out-of-range blocks exit via chunkoff
    k_score_r<<<(ES_ + SC_T - 1) / SC_T + R_, 256, 0, stream>>>(bufB, relW, eidx, head, tail,
                                                                roff, chkoff, outp, R_);
}

// Round 2
// 419.156 us; speedup vs baseline: 1.0097x; 1.0097x over previous
//
#include <hip/hip_runtime.h>
#include <hip/hip_bf16.h>

#define TD 128   // feature dim, fixed by problem
#define WS 136   // padded W-LDS row stride in bf16 (272 B: 16B-aligned, bank-uniform for b128)
#define SC_T 8   // triples per scoring block
#define NXCD 8   // XCDs on MI355X; degx has NXCD replicas

typedef __attribute__((ext_vector_type(8))) short bf16x8;   // 8 bf16 = 4 VGPR (MFMA A/B frag)
typedef __attribute__((ext_vector_type(4))) float f32x4;    // MFMA C/D frag

static __device__ __forceinline__ unsigned short f2bf(float f) {
    unsigned int u = __float_as_uint(f);
    u += 0x7fffu + ((u >> 16) & 1u);   // round-to-nearest-even
    return (unsigned short)(u >> 16);
}
static __device__ __forceinline__ float bf2f(unsigned short h) {
    return __uint_as_float((unsigned int)h << 16);
}

// ---------------- pass 1: degree + within-bucket rank, XCD-local atomics ----------------
// R1 post-mortem: neutral vs device-scope (atomic RMW executes at TCC either way; the
// ~1.6M-RMW channel-throughput floor is scope-independent). Kept: not worse, and the
// replica gather in k_place is L2-local.
__global__ __launch_bounds__(256) void k_rank(const int* __restrict__ ei, int* __restrict__ degx,
                                              int* __restrict__ rank, int E_, int N_) {
    unsigned xcc;
    asm volatile("s_getreg_b32 %0, hwreg(HW_REG_XCC_ID)" : "=s"(xcc));
    xcc &= (NXCD - 1);
    int e = blockIdx.x * 256 + threadIdx.x;
    if (e < E_) {
        int d = ei[E_ + e];   // dst = row 1
        int lr = __hip_atomic_fetch_add(&degx[(size_t)xcc * N_ + d], 1,
                                        __ATOMIC_RELAXED, __HIP_MEMORY_SCOPE_WORKGROUP);
        rank[e] = (lr << 3) | (int)xcc;
    }
}

// per node: exclusive scan of the 8 replica counts (in place -> per-XCD slot base),
// deg = total, dinv = deg^-1/2 (folds old k_dinv). All 8 streams coalesced (stride N).
__global__ __launch_bounds__(256) void k_merge(int* __restrict__ degx, int* __restrict__ deg,
                                               float* __restrict__ dinv, int n) {
    int i = blockIdx.x * 256 + threadIdx.x;
    if (i >= n) return;
    int run = 0;
#pragma unroll
    for (int x = 0; x < NXCD; ++x) {
        size_t idx = (size_t)x * n + i;
        int c = degx[idx];
        degx[idx] = run;
        run += c;
    }
    deg[i] = run;
    dinv[i] = (run > 0) ? 1.0f / sqrtf((float)run) : 0.0f;
}

// ---------------- exclusive scan (3-kernel hierarchical) ----------------
__global__ __launch_bounds__(256) void k_scan1(const int* __restrict__ deg, int* __restrict__ rowptr,
                                               int* __restrict__ bsums, int n) {
    __shared__ int wsum[4];
    int t = threadIdx.x;
    int base = blockIdx.x * 1024 + t * 4;
    int a0 = 0, a1 = 0, a2 = 0, a3 = 0;
    if (base + 3 < n) {
        int4 v = *(const int4*)(deg + base);
        a0 = v.x; a1 = v.y; a2 = v.z; a3 = v.w;
    } else {
        if (base     < n) a0 = deg[base];
        if (base + 1 < n) a1 = deg[base + 1];
        if (base + 2 < n) a2 = deg[base + 2];
        if (base + 3 < n) a3 = deg[base + 3];
    }
    int s1 = a0 + a1, s2 = s1 + a2, tot = s2 + a3;
    int lane = t & 63, wv = t >> 6;
    int x = tot;
#pragma unroll
    for (int off = 1; off < 64; off <<= 1) {
        int y = __shfl_up(x, off);
        if (lane >= off) x += y;
    }
    if (lane == 63) wsum[wv] = x;
    __syncthreads();
    int woff = 0;
    for (int w = 0; w < wv; ++w) woff += wsum[w];
    int excl = woff + x - tot;
    if (base     < n) rowptr[base]     = excl;
    if (base + 1 < n) rowptr[base + 1] = excl + a0;
    if (base + 2 < n) rowptr[base + 2] = excl + s1;
    if (base + 3 < n) rowptr[base + 3] = excl + s2;
    if (t == 255) bsums[blockIdx.x] = woff + x;   // block total
}

// parallel single-block scan of block sums (nb <= 1024)
__global__ __launch_bounds__(256) void k_scan2(int* __restrict__ bsums, int nb, int* __restrict__ rowptrN) {
    __shared__ int wsum[4];
    int t = threadIdx.x;
    int base = t * 4;
    int a0 = (base     < nb) ? bsums[base]     : 0;
    int a1 = (base + 1 < nb) ? bsums[base + 1] : 0;
    int a2 = (base + 2 < nb) ? bsums[base + 2] : 0;
    int a3 = (base + 3 < nb) ? bsums[base + 3] : 0;
    int s1 = a0 + a1, s2 = s1 + a2, tot = s2 + a3;
    int lane = t & 63, wv = t >> 6;
    int x = tot;
#pragma unroll
    for (int off = 1; off < 64; off <<= 1) {
        int y = __shfl_up(x, off);
        if (lane >= off) x += y;
    }
    if (lane == 63) wsum[wv] = x;
    __syncthreads();
    int woff = 0;
    for (int w = 0; w < wv; ++w) woff += wsum[w];
    int excl = woff + x - tot;
    if (base     < nb) bsums[base]     = excl;
    if (base + 1 < nb) bsums[base + 1] = excl + a0;
    if (base + 2 < nb) bsums[base + 2] = excl + s1;
    if (base + 3 < nb) bsums[base + 3] = excl + s2;
    if (t == 255) *rowptrN = woff + x;   // grand total = E
}

__global__ __launch_bounds__(256) void k_scan3(int* __restrict__ rowptr, const int* __restrict__ bsums, int n) {
    int i = blockIdx.x * 256 + threadIdx.x;
    if (i < n) rowptr[i] += bsums[i >> 10];
}

// ---------------- pass 2: atomic-free placement ----------------
__global__ __launch_bounds__(256) void k_place(const int* __restrict__ ei, const int* __restrict__ rowptr,
                                               const int* __restrict__ rank, const int* __restrict__ degx,
                                               int* __restrict__ esrc, int E_, int N_) {
    int e = blockIdx.x * 256 + threadIdx.x;
    if (e < E_) {
        int s = ei[e];
        int d = ei[E_ + e];
        int r = rank[e];
        int x = r & (NXCD - 1);
        int lr = r >> 3;
        esrc[rowptr[d] + degx[(size_t)x * N_ + d] + lr] = s;
    }
}

// ---------------- W transpose + hi/lo bf16 split ----------------
__global__ __launch_bounds__(256) void k_wsplit(const float* __restrict__ W1, const float* __restrict__ W2,
                                                unsigned short* __restrict__ Wt) {
    int i = blockIdx.x * 256 + threadIdx.x;   // 0 .. 2*16384-1
    int w = i >> 14;
    int idx = i & 16383;          // = k*128 + n  (coalesced read)
    int k = idx >> 7, n = idx & 127;
    float x = (w ? W2 : W1)[idx];
    unsigned short h = f2bf(x);
    unsigned short l = f2bf(x - bf2f(h));
    size_t base = (size_t)w * 32768;
    Wt[base + n * 128 + k] = h;
    Wt[base + 16384 + n * 128 + k] = l;
}

// ---------------- MFMA GEMM v5: W hi+lo staged to LDS once per block ----------------
// out[r][c] = bf16(scale[r] * sum_k X[r][k]*W[k][c]); f32-equiv precision via bf16 hi/lo split
// (A*B ~= Ah*Bh + Al*Bh + Ah*Bl). W lives in LDS (68KB padded, stride 136 = 16B-aligned +
// bank-uniform for b128), staged once per block; inner loop uses ds_read_b128. A-frags direct
// from global into registers. C stored straight to global. One __syncthreads total. 2 blocks/CU.
__global__ __launch_bounds__(256, 2) void k_gemm(const float* __restrict__ X,
                                                 const unsigned short* __restrict__ Wth,
                                                 const unsigned short* __restrict__ Wtl,
                                                 const float* __restrict__ scale,
                                                 unsigned short* __restrict__ out,
                                                 int nrows) {
    __shared__ __align__(16) unsigned short Wl[2][128 * WS];   // 68 KB (hi, lo)
    const int t = threadIdx.x;
    const int w = t >> 6;
    const int lane = t & 63;
    const int l15 = lane & 15;
    const int quad = lane >> 4;
    const int rbase = blockIdx.x * 64 + w * 16;   // wave's 16-row tile
    const int arow = rbase + l15;                 // this lane's A row
    const bool avalid = arow < nrows;

    // A: 8 float4 loads, issue immediately (independent of staging)
    float4 xa[4][2];
#pragma unroll
    for (int kc = 0; kc < 4; ++kc) {
        const float* src = X + (size_t)arow * TD + kc * 32 + quad * 8;
        xa[kc][0] = avalid ? *(const float4*)src       : make_float4(0.f, 0.f, 0.f, 0.f);
        xa[kc][1] = avalid ? *(const float4*)(src + 4) : make_float4(0.f, 0.f, 0.f, 0.f);
    }

    // stage W hi+lo -> padded LDS: 2048 uint4 per plane, 8 per thread
    {
        const uint4* gh = (const uint4*)Wth;
        const uint4* gl = (const uint4*)Wtl;
#pragma unroll
        for (int it = 0; it < 8; ++it) {
            int idx = t + it * 256;            // 0..2047
            int n = idx >> 4, kg = idx & 15;   // row n, k-group kg (8 bf16 each)
            uint4 vh = gh[idx];
            uint4 vl = gl[idx];
            *(uint4*)&Wl[0][n * WS + kg * 8] = vh;
            *(uint4*)&Wl[1][n * WS + kg * 8] = vl;
        }
    }

    // convert A to bf16 hi/lo fragments while staging is in flight
    bf16x8 ah[4], al[4];
#pragma unroll
    for (int kc = 0; kc < 4; ++kc) {
#pragma unroll
        for (int j = 0; j < 8; ++j) {
            float v = (j < 4) ? ((const float*)&xa[kc][0])[j] : ((const float*)&xa[kc][1])[j - 4];
            unsigned short h = f2bf(v);
            ah[kc][j] = (short)h;
            al[kc][j] = (short)f2bf(v - bf2f(h));
        }
    }
    __syncthreads();

    f32x4 acc[8];
#pragma unroll
    for (int b = 0; b < 8; ++b) acc[b] = (f32x4){0.f, 0.f, 0.f, 0.f};

#pragma unroll
    for (int kc = 0; kc < 4; ++kc) {
        const int koff = kc * 32 + quad * 8;
#pragma unroll
        for (int b = 0; b < 8; ++b) {
            const int boff = (b * 16 + l15) * WS + koff;
            bf16x8 bh = *(const bf16x8*)&Wl[0][boff];
            bf16x8 bl = *(const bf16x8*)&Wl[1][boff];
            acc[b] = __builtin_amdgcn_mfma_f32_16x16x32_bf16(ah[kc], bh, acc[b], 0, 0, 0);
            acc[b] = __builtin_amdgcn_mfma_f32_16x16x32_bf16(al[kc], bh, acc[b], 0, 0, 0);
            acc[b] = __builtin_amdgcn_mfma_f32_16x16x32_bf16(ah[kc], bl, acc[b], 0, 0, 0);
        }
    }

    // epilogue: C/D layout col=lane&15, row=quad*4+reg -> scale + direct bf16 global stores
    {
        int grow = rbase + quad * 4;              // multiple of 4; nrows % 4 == 0
        if (grow < nrows) {
            float4 s4 = *(const float4*)&scale[grow];
#pragma unroll
            for (int b = 0; b < 8; ++b) {
                int col = b * 16 + l15;
                out[(size_t)(grow + 0) * TD + col] = f2bf(acc[b][0] * s4.x);
                out[(size_t)(grow + 1) * TD + col] = f2bf(acc[b][1] * s4.y);
                out[(size_t)(grow + 2) * TD + col] = f2bf(acc[b][2] * s4.z);
                out[(size_t)(grow + 3) * TD + col] = f2bf(acc[b][3] * s4.w);
            }
        }
    }
}

// ---------------- CSR aggregation: bf16 gather, f32 accumulate, 4-edge unrolled ----------------
// R2: f64 accumulate was ~half the kernel (VALUBusy 42%: cvt_f64 + half-rate v_add_f64).
// bufA is already bf16-quantized (~4e-3 rel noise) so f32 accumulation of ~16 terms adds
// negligible error. Two accumulator banks (even/odd edges) halve the add dependency chain;
// 4 gathers in flight per iteration for 2x MLP vs the old 2-edge loop.
#define ACC8(p, u) \
    p##0 += __uint_as_float(u.x << 16); p##1 += __uint_as_float(u.x & 0xffff0000u); \
    p##2 += __uint_as_float(u.y << 16); p##3 += __uint_as_float(u.y & 0xffff0000u); \
    p##4 += __uint_as_float(u.z << 16); p##5 += __uint_as_float(u.z & 0xffff0000u); \
    p##6 += __uint_as_float(u.w << 16); p##7 += __uint_as_float(u.w & 0xffff0000u);

__global__ __launch_bounds__(256) void k_agg(const unsigned short* __restrict__ hs, const int* __restrict__ rowptr,
                                             const int* __restrict__ esrc, const float* __restrict__ dinv,
                                             const float* __restrict__ bias, float* __restrict__ out,
                                             int n, int relu) {
    int node = blockIdx.x * 16 + (threadIdx.x >> 4);
    int lane = threadIdx.x & 15;
    if (node >= n) return;
    int s = rowptr[node], e = rowptr[node + 1];
    const uint4* h16 = (const uint4*)hs;
    float a0 = 0.f, a1 = 0.f, a2 = 0.f, a3 = 0.f, a4 = 0.f, a5 = 0.f, a6 = 0.f, a7 = 0.f;
    float c0 = 0.f, c1 = 0.f, c2 = 0.f, c3 = 0.f, c4 = 0.f, c5 = 0.f, c6 = 0.f, c7 = 0.f;
    int i = s;
    for (; i + 4 <= e; i += 4) {
        int s0 = esrc[i], s1 = esrc[i + 1], s2 = esrc[i + 2], s3 = esrc[i + 3];
        uint4 u0 = h16[(size_t)s0 * 16 + lane];
        uint4 u1 = h16[(size_t)s1 * 16 + lane];
        uint4 u2 = h16[(size_t)s2 * 16 + lane];
        uint4 u3 = h16[(size_t)s3 * 16 + lane];
        ACC8(a, u0)
        ACC8(c, u1)
        ACC8(a, u2)
        ACC8(c, u3)
    }
    for (; i < e; ++i) {
        uint4 u = h16[(size_t)esrc[i] * 16 + lane];
        ACC8(a, u)
    }
    a0 += c0; a1 += c1; a2 += c2; a3 += c3;
    a4 += c4; a5 += c5; a6 += c6; a7 += c7;
    float di = dinv[node];
    float4 b0 = ((const float4*)bias)[lane * 2];
    float4 b1 = ((const float4*)bias)[lane * 2 + 1];
    float o0 = fmaf(di, a0, b0.x);
    float o1 = fmaf(di, a1, b0.y);
    float o2 = fmaf(di, a2, b0.z);
    float o3 = fmaf(di, a3, b0.w);
    float o4 = fmaf(di, a4, b1.x);
    float o5 = fmaf(di, a5, b1.y);
    float o6 = fmaf(di, a6, b1.z);
    float o7 = fmaf(di, a7, b1.w);
    if (relu) {
        o0 = fmaxf(o0, 0.f); o1 = fmaxf(o1, 0.f); o2 = fmaxf(o2, 0.f); o3 = fmaxf(o3, 0.f);
        o4 = fmaxf(o4, 0.f); o5 = fmaxf(o5, 0.f); o6 = fmaxf(o6, 0.f); o7 = fmaxf(o7, 0.f);
    }
    ((float4*)out)[(size_t)node * 32 + lane * 2]     = make_float4(o0, o1, o2, o3);
    ((float4*)out)[(size_t)node * 32 + lane * 2 + 1] = make_float4(o4, o5, o6, o7);
}

// ---------------- relation bucketing: block-aggregated histograms (16 global atomics/block) ----------------
__global__ __launch_bounds__(256) void k_rcnt(const int* __restrict__ rel, int* __restrict__ rcount, int es) {
    __shared__ int lh[16];
    int t = threadIdx.x;
    if (t < 16) lh[t] = 0;
    __syncthreads();
#pragma unroll
    for (int i = 0; i < 4; ++i) {
        int e = blockIdx.x * 1024 + i * 256 + t;
        if (e < es) atomicAdd(&lh[rel[e]], 1);
    }
    __syncthreads();
    if (t < 16 && lh[t]) atomicAdd(&rcount[t], lh[t]);
}

__global__ void k_roff(const int* __restrict__ rcount, int* __restrict__ roff,
                       int* __restrict__ chunkoff, int nr) {
    if (threadIdx.x == 0 && blockIdx.x == 0) {
        int run = 0, crun = 0;
        for (int r = 0; r < nr; ++r) {
            roff[r] = run; chunkoff[r] = crun;
            run += rcount[r]; crun += (rcount[r] + SC_T - 1) / SC_T;
        }
        roff[nr] = run; chunkoff[nr] = crun;
    }
}

__global__ __launch_bounds__(256) void k_bucket(const int* __restrict__ rel, int* __restrict__ cursor,
                                                int* __restrict__ eidx, int es) {
    __shared__ int lh[16];
    __shared__ int lbase[16];
    int t = threadIdx.x;
    if (t < 16) lh[t] = 0;
    __syncthreads();
    int r[4], lr[4];
#pragma unroll
    for (int i = 0; i < 4; ++i) {
        int e = blockIdx.x * 1024 + i * 256 + t;
        if (e < es) {
            r[i] = rel[e];
            lr[i] = atomicAdd(&lh[r[i]], 1);   // LDS atomic: intra-block rank
        } else r[i] = -1;
    }
    __syncthreads();
    if (t < 16) lbase[t] = lh[t] ? atomicAdd(&cursor[t], lh[t]) : 0;   // reserve range
    __syncthreads();
#pragma unroll
    for (int i = 0; i < 4; ++i)
        if (r[i] >= 0) eidx[lbase[r[i]] + lr[i]] = blockIdx.x * 1024 + i * 256 + t;
}

// ---------------- batched scoring: SC_T triples of ONE relation per block, W[r] staged once ----------------
__global__ __launch_bounds__(256) void k_score_r(const float* __restrict__ z, const float* __restrict__ relW,
                                                 const int* __restrict__ eidx, const int* __restrict__ head,
                                                 const int* __restrict__ tail, const int* __restrict__ roff,
                                                 const int* __restrict__ chunkoff, float* __restrict__ out,
                                                 int R_) {
    __shared__ __align__(16) float Wl[TD * TD];      // 64 KB
    __shared__ __align__(16) float zhL[SC_T * TD];   // 4 KB
    __shared__ __align__(16) float ztL[SC_T * TD];   // 4 KB
    __shared__ int eids[SC_T];
    __shared__ int co[17], ro[17];
    __shared__ float red[4][SC_T];
    const int t = threadIdx.x;
    const int b = blockIdx.x;
    if (t < 17 && t <= R_) { co[t] = chunkoff[t]; ro[t] = roff[t]; }
    __syncthreads();
    int r = 0;
    while (r < R_ && co[r + 1] <= b) ++r;
    if (r >= R_) return;                       // uniform: all threads exit together
    const int base = ro[r] + (b - co[r]) * SC_T;
    const int nt = min(SC_T, ro[r + 1] - base);
    if (t < SC_T) eids[t] = (t < nt) ? eidx[base + t] : -1;
    __syncthreads();
    {   // stage zh/zt: 256 float4, 1 per thread
        int tt = t >> 5, c4 = t & 31;
        float4 vh = make_float4(0.f, 0.f, 0.f, 0.f), vt = vh;
        int e = eids[tt];
        if (e >= 0) {
            vh = ((const float4*)(z + (size_t)head[e] * TD))[c4];
            vt = ((const float4*)(z + (size_t)tail[e] * TD))[c4];
        }
        ((float4*)(zhL + tt * TD))[c4] = vh;
        ((float4*)(ztL + tt * TD))[c4] = vt;
    }
    {   // stage W[r]: 4096 float4
        const float4* W4 = (const float4*)(relW + (size_t)r * TD * TD);
        float4* Wl4 = (float4*)Wl;
#pragma unroll
        for (int i = 0; i < 16; ++i) Wl4[t + i * 256] = W4[t + i * 256];
    }
    __syncthreads();

    const int c  = (t & 31) * 4;    // cols c..c+3
    const int i0 = (t >> 5) * 16;   // 16-row i segment
    float4 acc[SC_T];
#pragma unroll
    for (int u = 0; u < SC_T; ++u) acc[u] = make_float4(0.f, 0.f, 0.f, 0.f);
#pragma unroll 4
    for (int i = i0; i < i0 + 16; ++i) {
        float4 wv = *(const float4*)&Wl[i * TD + c];
#pragma unroll
        for (int u = 0; u < SC_T; ++u) {
            float h = zhL[u * TD + i];
            acc[u].x = fmaf(h, wv.x, acc[u].x);
            acc[u].y = fmaf(h, wv.y, acc[u].y);
            acc[u].z = fmaf(h, wv.z, acc[u].z);
            acc[u].w = fmaf(h, wv.w, acc[u].w);
        }
    }
    float pth[SC_T];
#pragma unroll
    for (int u = 0; u < SC_T; ++u) {
        float4 z4 = *(const float4*)&ztL[u * TD + c];
        pth[u] = acc[u].x * z4.x + acc[u].y * z4.y + acc[u].z * z4.z + acc[u].w * z4.w;
    }
#pragma unroll
    for (int off = 32; off > 0; off >>= 1)
#pragma unroll
        for (int u = 0; u < SC_T; ++u) pth[u] += __shfl_down(pth[u], off);
    if ((t & 63) == 0) {
        int wv = t >> 6;
#pragma unroll
        for (int u = 0; u < SC_T; ++u) red[wv][u] = pth[u];
    }
    __syncthreads();
    if (t < SC_T) {
        int e = eids[t];
        if (e >= 0) out[e] = red[0][t] + red[1][t] + red[2][t] + red[3][t];
    }
}

extern "C" void kernel_launch(void* const* d_in, const int* in_sizes, int n_in,
                              void* d_out, int out_size, void* d_ws, size_t ws_size,
                              hipStream_t stream) {
    const float* x0   = (const float*)d_in[0];
    const float* W1   = (const float*)d_in[1];
    const float* b1   = (const float*)d_in[2];
    const float* W2   = (const float*)d_in[3];
    const float* b2   = (const float*)d_in[4];
    const float* relW = (const float*)d_in[5];
    const int*   ei   = (const int*)d_in[6];
    const int*   rel  = (const int*)d_in[7];
    const int*   head = (const int*)d_in[8];
    const int*   tail = (const int*)d_in[9];
    float* outp = (float*)d_out;

    const int N_  = in_sizes[0] / TD;
    const int E_  = in_sizes[6] / 2;
    const int ES_ = in_sizes[7];
    const int R_  = in_sizes[5] / (TD * TD);
    const int nb  = (N_ + 1023) / 1024;
    const int ntiles64 = (N_ + 63) / 64;

    char* p = (char*)d_ws;
    auto alloc = [&](size_t bytes) { char* r = p; p += (bytes + 255) & ~(size_t)255; return r; };
    int*            deg    = (int*)           alloc((size_t)N_ * 4);
    int*            degx   = (int*)           alloc((size_t)NXCD * N_ * 4);   // per-XCD replicas
    float*          dinv   = (float*)         alloc((size_t)N_ * 4);
    int*            rowptr = (int*)           alloc(((size_t)N_ + 1) * 4);
    int*            bsums  = (int*)           alloc((size_t)nb * 4);
    int*            esrc   = (int*)           alloc((size_t)E_ * 4);
    unsigned short* Wt     = (unsigned short*)alloc((size_t)4 * 16384 * 2);   // W1h,W1l,W2h,W2l
    int*            rcount = (int*)           alloc((size_t)R_ * 4);
    int*            roff   = (int*)           alloc(((size_t)R_ + 1) * 4);
    int*            chkoff = (int*)           alloc(((size_t)R_ + 1) * 4);
    int*            cursor = (int*)           alloc((size_t)R_ * 4);
    int*            eidx   = (int*)           alloc((size_t)ES_ * 4);
    unsigned short* bufA   = (unsigned short*)alloc((size_t)N_ * TD * 2);     // bf16 h-scaled
    float*          bufB   = (float*)         alloc((size_t)N_ * TD * 4);     // f32 conv out
    int*            rank   = (int*)bufA;   // alias: dead before first k_gemm writes bufA (E*4 <= N*TD*2)

    hipMemsetAsync(degx, 0, (size_t)NXCD * N_ * 4, stream);
    hipMemsetAsync(rcount, 0, (size_t)R_ * 4, stream);
    k_rank  <<<(E_ + 255) / 256, 256, 0, stream>>>(ei, degx, rank, E_, N_);
    k_merge <<<(N_ + 255) / 256, 256, 0, stream>>>(degx, deg, dinv, N_);
    k_scan1 <<<nb, 256, 0, stream>>>(deg, rowptr, bsums, N_);
    k_scan2 <<<1, 256, 0, stream>>>(bsums, nb, rowptr + N_);
    k_scan3 <<<(N_ + 255) / 256, 256, 0, stream>>>(rowptr, bsums, N_);
    k_place <<<(E_ + 255) / 256, 256, 0, stream>>>(ei, rowptr, rank, degx, esrc, E_, N_);
    k_wsplit<<<128, 256, 0, stream>>>(W1, W2, Wt);

    // relation bucketing for scoring (block-aggregated atomics)
    k_rcnt  <<<(ES_ + 1023) / 1024, 256, 0, stream>>>(rel, rcount, ES_);
    k_roff  <<<1, 64, 0, stream>>>(rcount, roff, chkoff, R_);
    hipMemcpyAsync(cursor, roff, (size_t)R_ * 4, hipMemcpyDeviceToDevice, stream);
    k_bucket<<<(ES_ + 1023) / 1024, 256, 0, stream>>>(rel, cursor, eidx, ES_);

    // conv1: bufA = bf16(dinv * (x0 @ W1)); bufB = relu(dinv*agg(bufA) + b1)
    k_gemm<<<ntiles64, 256, 0, stream>>>(x0, Wt, Wt + 16384, dinv, bufA, N_);
    k_agg <<<(N_ + 15) / 16, 256, 0, stream>>>(bufA, rowptr, esrc, dinv, b1, bufB, N_, 1);
    // conv2: bufA = bf16(dinv * (bufB @ W2)); bufB = dinv*agg(bufA) + b2  (= z)
    k_gemm<<<ntiles64, 256, 0, stream>>>(bufB, Wt + 32768, Wt + 49152, dinv, bufA, N_);
    k_agg <<<(N_ + 15) / 16, 256, 0, stream>>>(bufA, rowptr, esrc, dinv, b2, bufB, N_, 0);

    // scoring: blocks = chunks (upper bound ES/SC_T + R); out-of-range blocks exit via chunkoff
    k_score_r<<<(ES_ + SC_T - 1) / SC_T + R_, 256, 0, stream>>>(bufB, relW, eidx, head, tail,
                                                                roff, chkoff, outp, R_);
}

// Round 3
// 364.176 us; speedup vs baseline: 1.1622x; 1.1510x over previous
//
#include <hip/hip_runtime.h>
#include <hip/hip_bf16.h>

#define TD 128    // feature dim, fixed by problem
#define WS 136    // padded W-LDS row stride in bf16 (272 B: 16B-aligned, bank-uniform for b128)
#define SC_T 8    // triples per scoring block
#define BKT_SH 7  // 128 nodes per CSR bucket (NB = ceil(N/128) <= 1024 for N <= 131072)
#define NBLK 256  // partition blocks for hist/scat passes

typedef __attribute__((ext_vector_type(8))) short bf16x8;   // 8 bf16 = 4 VGPR (MFMA A/B frag)
typedef __attribute__((ext_vector_type(4))) float f32x4;    // MFMA C/D frag

static __device__ __forceinline__ unsigned short f2bf(float f) {
    unsigned int u = __float_as_uint(f);
    u += 0x7fffu + ((u >> 16) & 1u);   // round-to-nearest-even
    return (unsigned short)(u >> 16);
}
static __device__ __forceinline__ float bf2f(unsigned short h) {
    return __uint_as_float((unsigned int)h << 16);
}

// ================= atomic-free CSR build =================
// R3: global atomicAdd-with-return write-throughs ~32B/op to HBM regardless of scope
// (R1/R2 evidence: 56MB WRITE_SIZE, ~24 atomics/ns floor, 67us). Replaced by LDS-histogram
// multi-split: bucket = dst>>7 (128 nodes/bucket), per-block LDS counts -> two-level scan ->
// scatter packed (src<<7 | dst&127) into bucket-grouped ebuf -> per-bucket exact counting
// sort builds rowptr/dinv/esrc. Zero global atomics end to end.

// pass 1: per-block bucket histogram. bh layout [bucket][blk] so scanA reads coalesced.
__global__ __launch_bounds__(256) void kc_hist(const int* __restrict__ ei, int* __restrict__ bh,
                                               int E_, int NB, int chunk) {
    __shared__ int lh[1024];
    int t = threadIdx.x, blk = blockIdx.x;
    for (int j = t; j < NB; j += 256) lh[j] = 0;
    __syncthreads();
    int e0 = blk * chunk, e1 = min(E_, e0 + chunk);
    for (int e = e0 + t; e < e1; e += 256)
        atomicAdd(&lh[ei[E_ + e] >> BKT_SH], 1);   // LDS atomic
    __syncthreads();
    for (int j = t; j < NB; j += 256) bh[(size_t)j * NBLK + blk] = lh[j];
}

// pass 2a: per bucket, exclusive scan over the NBLK block counts (in place); tot[b] = bucket size
__global__ __launch_bounds__(64) void kc_scanA(int* __restrict__ bh, int* __restrict__ tot, int NB) {
    int b = blockIdx.x, l = threadIdx.x;
    int* row = bh + (size_t)b * NBLK;
    int run = 0;
#pragma unroll
    for (int g = 0; g < NBLK / 64; ++g) {
        int v = row[g * 64 + l];
        int x = v;
#pragma unroll
        for (int off = 1; off < 64; off <<= 1) {
            int y = __shfl_up(x, off);
            if (l >= off) x += y;
        }
        row[g * 64 + l] = run + x - v;   // exclusive within bucket
        run += __shfl(x, 63);
    }
    if (l == 0) tot[b] = run;
}

// pass 2b: single-block exclusive scan of bucket totals -> boff[0..NB], rowptr[N] = E
__global__ __launch_bounds__(256) void kc_scanB(const int* __restrict__ tot, int* __restrict__ boff,
                                                int NB, int* __restrict__ rowptrN) {
    __shared__ int wsum[4];
    int t = threadIdx.x;
    int base = t * 4;
    int a0 = (base     < NB) ? tot[base]     : 0;
    int a1 = (base + 1 < NB) ? tot[base + 1] : 0;
    int a2 = (base + 2 < NB) ? tot[base + 2] : 0;
    int a3 = (base + 3 < NB) ? tot[base + 3] : 0;
    int s1 = a0 + a1, s2 = s1 + a2, tt = s2 + a3;
    int lane = t & 63, wv = t >> 6;
    int x = tt;
#pragma unroll
    for (int off = 1; off < 64; off <<= 1) {
        int y = __shfl_up(x, off);
        if (lane >= off) x += y;
    }
    if (lane == 63) wsum[wv] = x;
    __syncthreads();
    int woff = 0;
    for (int w = 0; w < wv; ++w) woff += wsum[w];
    int excl = woff + x - tt;
    if (base     < NB) boff[base]     = excl;
    if (base + 1 < NB) boff[base + 1] = excl + a0;
    if (base + 2 < NB) boff[base + 2] = excl + s1;
    if (base + 3 < NB) boff[base + 3] = excl + s2;
    if (t == 255) { boff[NB] = woff + x; *rowptrN = woff + x; }
}

// pass 3: scatter edges into bucket-grouped ebuf, packed (src<<7)|(dst&127). LDS-atomic ranks.
__global__ __launch_bounds__(256) void kc_scat(const int* __restrict__ ei, const int* __restrict__ bh,
                                               const int* __restrict__ boff, int* __restrict__ ebuf,
                                               int E_, int NB, int chunk) {
    __shared__ int lh[1024];
    int t = threadIdx.x, blk = blockIdx.x;
    for (int j = t; j < NB; j += 256) lh[j] = 0;
    __syncthreads();
    int e0 = blk * chunk, e1 = min(E_, e0 + chunk);
    for (int e = e0 + t; e < e1; e += 256) {
        int s = ei[e];
        int d = ei[E_ + e];
        int b = d >> BKT_SH;
        int lr = atomicAdd(&lh[b], 1);   // LDS atomic: rank within (block, bucket)
        int slot = boff[b] + bh[(size_t)b * NBLK + blk] + lr;
        ebuf[slot] = (s << BKT_SH) | (d & ((1 << BKT_SH) - 1));
    }
}

// pass 4: one block per bucket -> exact per-node counting sort. Writes rowptr, dinv, esrc.
__global__ __launch_bounds__(256) void kc_build(const int* __restrict__ ebuf, const int* __restrict__ boff,
                                                int* __restrict__ rowptr, float* __restrict__ dinv,
                                                int* __restrict__ esrc, int n) {
    __shared__ int hist[128], excl[128], cur[128];
    __shared__ int w0;
    int b = blockIdx.x, t = threadIdx.x;
    int node0 = b << BKT_SH;
    int s = boff[b], e = boff[b + 1];
    if (t < 128) { hist[t] = 0; cur[t] = 0; }
    __syncthreads();
    for (int i = s + t; i < e; i += 256)
        atomicAdd(&hist[ebuf[i] & 127], 1);   // LDS atomic
    __syncthreads();
    // scan the 128 counts (waves 0,1 active; uniform syncs)
    int v = (t < 128) ? hist[t] : 0;
    int lane = t & 63, wv = t >> 6;
    int x = v;
#pragma unroll
    for (int off = 1; off < 64; off <<= 1) {
        int y = __shfl_up(x, off);
        if (lane >= off) x += y;
    }
    if (t == 63) w0 = x;
    __syncthreads();
    if (t < 128) {
        int ex = x - v + (wv == 1 ? w0 : 0);
        excl[t] = ex;
        int node = node0 + t;
        if (node < n) {
            rowptr[node] = s + ex;
            dinv[node] = (v > 0) ? 1.0f / sqrtf((float)v) : 0.0f;
        }
    }
    __syncthreads();
    for (int i = s + t; i < e; i += 256) {
        int p = ebuf[i];
        int loc = p & 127;
        int lr = atomicAdd(&cur[loc], 1);   // LDS atomic
        esrc[s + excl[loc] + lr] = p >> BKT_SH;
    }
}

// ---------------- W transpose + hi/lo bf16 split ----------------
__global__ __launch_bounds__(256) void k_wsplit(const float* __restrict__ W1, const float* __restrict__ W2,
                                                unsigned short* __restrict__ Wt) {
    int i = blockIdx.x * 256 + threadIdx.x;   // 0 .. 2*16384-1
    int w = i >> 14;
    int idx = i & 16383;          // = k*128 + n  (coalesced read)
    int k = idx >> 7, n = idx & 127;
    float x = (w ? W2 : W1)[idx];
    unsigned short h = f2bf(x);
    unsigned short l = f2bf(x - bf2f(h));
    size_t base = (size_t)w * 32768;
    Wt[base + n * 128 + k] = h;
    Wt[base + 16384 + n * 128 + k] = l;
}

// ---------------- MFMA GEMM v5: W hi+lo staged to LDS once per block ----------------
// out[r][c] = bf16(scale[r] * sum_k X[r][k]*W[k][c]); f32-equiv precision via bf16 hi/lo split
// (A*B ~= Ah*Bh + Al*Bh + Ah*Bl). W lives in LDS (68KB padded, stride 136 = 16B-aligned +
// bank-uniform for b128), staged once per block; inner loop uses ds_read_b128. A-frags direct
// from global into registers. C stored straight to global. One __syncthreads total. 2 blocks/CU.
__global__ __launch_bounds__(256, 2) void k_gemm(const float* __restrict__ X,
                                                 const unsigned short* __restrict__ Wth,
                                                 const unsigned short* __restrict__ Wtl,
                                                 const float* __restrict__ scale,
                                                 unsigned short* __restrict__ out,
                                                 int nrows) {
    __shared__ __align__(16) unsigned short Wl[2][128 * WS];   // 68 KB (hi, lo)
    const int t = threadIdx.x;
    const int w = t >> 6;
    const int lane = t & 63;
    const int l15 = lane & 15;
    const int quad = lane >> 4;
    const int rbase = blockIdx.x * 64 + w * 16;   // wave's 16-row tile
    const int arow = rbase + l15;                 // this lane's A row
    const bool avalid = arow < nrows;

    // A: 8 float4 loads, issue immediately (independent of staging)
    float4 xa[4][2];
#pragma unroll
    for (int kc = 0; kc < 4; ++kc) {
        const float* src = X + (size_t)arow * TD + kc * 32 + quad * 8;
        xa[kc][0] = avalid ? *(const float4*)src       : make_float4(0.f, 0.f, 0.f, 0.f);
        xa[kc][1] = avalid ? *(const float4*)(src + 4) : make_float4(0.f, 0.f, 0.f, 0.f);
    }

    // stage W hi+lo -> padded LDS: 2048 uint4 per plane, 8 per thread
    {
        const uint4* gh = (const uint4*)Wth;
        const uint4* gl = (const uint4*)Wtl;
#pragma unroll
        for (int it = 0; it < 8; ++it) {
            int idx = t + it * 256;            // 0..2047
            int n = idx >> 4, kg = idx & 15;   // row n, k-group kg (8 bf16 each)
            uint4 vh = gh[idx];
            uint4 vl = gl[idx];
            *(uint4*)&Wl[0][n * WS + kg * 8] = vh;
            *(uint4*)&Wl[1][n * WS + kg * 8] = vl;
        }
    }

    // convert A to bf16 hi/lo fragments while staging is in flight
    bf16x8 ah[4], al[4];
#pragma unroll
    for (int kc = 0; kc < 4; ++kc) {
#pragma unroll
        for (int j = 0; j < 8; ++j) {
            float v = (j < 4) ? ((const float*)&xa[kc][0])[j] : ((const float*)&xa[kc][1])[j - 4];
            unsigned short h = f2bf(v);
            ah[kc][j] = (short)h;
            al[kc][j] = (short)f2bf(v - bf2f(h));
        }
    }
    __syncthreads();

    f32x4 acc[8];
#pragma unroll
    for (int b = 0; b < 8; ++b) acc[b] = (f32x4){0.f, 0.f, 0.f, 0.f};

#pragma unroll
    for (int kc = 0; kc < 4; ++kc) {
        const int koff = kc * 32 + quad * 8;
#pragma unroll
        for (int b = 0; b < 8; ++b) {
            const int boff = (b * 16 + l15) * WS + koff;
            bf16x8 bh = *(const bf16x8*)&Wl[0][boff];
            bf16x8 bl = *(const bf16x8*)&Wl[1][boff];
            acc[b] = __builtin_amdgcn_mfma_f32_16x16x32_bf16(ah[kc], bh, acc[b], 0, 0, 0);
            acc[b] = __builtin_amdgcn_mfma_f32_16x16x32_bf16(al[kc], bh, acc[b], 0, 0, 0);
            acc[b] = __builtin_amdgcn_mfma_f32_16x16x32_bf16(ah[kc], bl, acc[b], 0, 0, 0);
        }
    }

    // epilogue: C/D layout col=lane&15, row=quad*4+reg -> scale + direct bf16 global stores
    {
        int grow = rbase + quad * 4;              // multiple of 4; nrows % 4 == 0
        if (grow < nrows) {
            float4 s4 = *(const float4*)&scale[grow];
#pragma unroll
            for (int b = 0; b < 8; ++b) {
                int col = b * 16 + l15;
                out[(size_t)(grow + 0) * TD + col] = f2bf(acc[b][0] * s4.x);
                out[(size_t)(grow + 1) * TD + col] = f2bf(acc[b][1] * s4.y);
                out[(size_t)(grow + 2) * TD + col] = f2bf(acc[b][2] * s4.z);
                out[(size_t)(grow + 3) * TD + col] = f2bf(acc[b][3] * s4.w);
            }
        }
    }
}

// ---------------- CSR aggregation: bf16 gather, f32 accumulate, 4-edge unrolled ----------------
// R2: f64 accumulate was ~half the kernel (VALUBusy 42%). bufA is bf16-quantized (~4e-3 rel
// noise) so f32 accumulation of ~16 terms is negligible error. Two accumulator banks halve
// the add dependency chain; 4 gathers in flight per iteration.
#define ACC8(p, u) \
    p##0 += __uint_as_float(u.x << 16); p##1 += __uint_as_float(u.x & 0xffff0000u); \
    p##2 += __uint_as_float(u.y << 16); p##3 += __uint_as_float(u.y & 0xffff0000u); \
    p##4 += __uint_as_float(u.z << 16); p##5 += __uint_as_float(u.z & 0xffff0000u); \
    p##6 += __uint_as_float(u.w << 16); p##7 += __uint_as_float(u.w & 0xffff0000u);

__global__ __launch_bounds__(256) void k_agg(const unsigned short* __restrict__ hs, const int* __restrict__ rowptr,
                                             const int* __restrict__ esrc, const float* __restrict__ dinv,
                                             const float* __restrict__ bias, float* __restrict__ out,
                                             int n, int relu) {
    int node = blockIdx.x * 16 + (threadIdx.x >> 4);
    int lane = threadIdx.x & 15;
    if (node >= n) return;
    int s = rowptr[node], e = rowptr[node + 1];
    const uint4* h16 = (const uint4*)hs;
    float a0 = 0.f, a1 = 0.f, a2 = 0.f, a3 = 0.f, a4 = 0.f, a5 = 0.f, a6 = 0.f, a7 = 0.f;
    float c0 = 0.f, c1 = 0.f, c2 = 0.f, c3 = 0.f, c4 = 0.f, c5 = 0.f, c6 = 0.f, c7 = 0.f;
    int i = s;
    for (; i + 4 <= e; i += 4) {
        int s0 = esrc[i], s1 = esrc[i + 1], s2 = esrc[i + 2], s3 = esrc[i + 3];
        uint4 u0 = h16[(size_t)s0 * 16 + lane];
        uint4 u1 = h16[(size_t)s1 * 16 + lane];
        uint4 u2 = h16[(size_t)s2 * 16 + lane];
        uint4 u3 = h16[(size_t)s3 * 16 + lane];
        ACC8(a, u0)
        ACC8(c, u1)
        ACC8(a, u2)
        ACC8(c, u3)
    }
    for (; i < e; ++i) {
        uint4 u = h16[(size_t)esrc[i] * 16 + lane];
        ACC8(a, u)
    }
    a0 += c0; a1 += c1; a2 += c2; a3 += c3;
    a4 += c4; a5 += c5; a6 += c6; a7 += c7;
    float di = dinv[node];
    float4 b0 = ((const float4*)bias)[lane * 2];
    float4 b1 = ((const float4*)bias)[lane * 2 + 1];
    float o0 = fmaf(di, a0, b0.x);
    float o1 = fmaf(di, a1, b0.y);
    float o2 = fmaf(di, a2, b0.z);
    float o3 = fmaf(di, a3, b0.w);
    float o4 = fmaf(di, a4, b1.x);
    float o5 = fmaf(di, a5, b1.y);
    float o6 = fmaf(di, a6, b1.z);
    float o7 = fmaf(di, a7, b1.w);
    if (relu) {
        o0 = fmaxf(o0, 0.f); o1 = fmaxf(o1, 0.f); o2 = fmaxf(o2, 0.f); o3 = fmaxf(o3, 0.f);
        o4 = fmaxf(o4, 0.f); o5 = fmaxf(o5, 0.f); o6 = fmaxf(o6, 0.f); o7 = fmaxf(o7, 0.f);
    }
    ((float4*)out)[(size_t)node * 32 + lane * 2]     = make_float4(o0, o1, o2, o3);
    ((float4*)out)[(size_t)node * 32 + lane * 2 + 1] = make_float4(o4, o5, o6, o7);
}

// ---------------- relation bucketing: block-aggregated histograms (16 global atomics/block) ----------------
__global__ __launch_bounds__(256) void k_rcnt(const int* __restrict__ rel, int* __restrict__ rcount, int es) {
    __shared__ int lh[16];
    int t = threadIdx.x;
    if (t < 16) lh[t] = 0;
    __syncthreads();
#pragma unroll
    for (int i = 0; i < 4; ++i) {
        int e = blockIdx.x * 1024 + i * 256 + t;
        if (e < es) atomicAdd(&lh[rel[e]], 1);
    }
    __syncthreads();
    if (t < 16 && lh[t]) atomicAdd(&rcount[t], lh[t]);
}

__global__ void k_roff(const int* __restrict__ rcount, int* __restrict__ roff,
                       int* __restrict__ chunkoff, int nr) {
    if (threadIdx.x == 0 && blockIdx.x == 0) {
        int run = 0, crun = 0;
        for (int r = 0; r < nr; ++r) {
            roff[r] = run; chunkoff[r] = crun;
            run += rcount[r]; crun += (rcount[r] + SC_T - 1) / SC_T;
        }
        roff[nr] = run; chunkoff[nr] = crun;
    }
}

__global__ __launch_bounds__(256) void k_bucket(const int* __restrict__ rel, int* __restrict__ cursor,
                                                int* __restrict__ eidx, int es) {
    __shared__ int lh[16];
    __shared__ int lbase[16];
    int t = threadIdx.x;
    if (t < 16) lh[t] = 0;
    __syncthreads();
    int r[4], lr[4];
#pragma unroll
    for (int i = 0; i < 4; ++i) {
        int e = blockIdx.x * 1024 + i * 256 + t;
        if (e < es) {
            r[i] = rel[e];
            lr[i] = atomicAdd(&lh[r[i]], 1);   // LDS atomic: intra-block rank
        } else r[i] = -1;
    }
    __syncthreads();
    if (t < 16) lbase[t] = lh[t] ? atomicAdd(&cursor[t], lh[t]) : 0;   // reserve range
    __syncthreads();
#pragma unroll
    for (int i = 0; i < 4; ++i)
        if (r[i] >= 0) eidx[lbase[r[i]] + lr[i]] = blockIdx.x * 1024 + i * 256 + t;
}

// ---------------- batched scoring: SC_T triples of ONE relation per block, W[r] staged once ----------------
__global__ __launch_bounds__(256) void k_score_r(const float* __restrict__ z, const float* __restrict__ relW,
                                                 const int* __restrict__ eidx, const int* __restrict__ head,
                                                 const int* __restrict__ tail, const int* __restrict__ roff,
                                                 const int* __restrict__ chunkoff, float* __restrict__ out,
                                                 int R_) {
    __shared__ __align__(16) float Wl[TD * TD];      // 64 KB
    __shared__ __align__(16) float zhL[SC_T * TD];   // 4 KB
    __shared__ __align__(16) float ztL[SC_T * TD];   // 4 KB
    __shared__ int eids[SC_T];
    __shared__ int co[17], ro[17];
    __shared__ float red[4][SC_T];
    const int t = threadIdx.x;
    const int b = blockIdx.x;
    if (t < 17 && t <= R_) { co[t] = chunkoff[t]; ro[t] = roff[t]; }
    __syncthreads();
    int r = 0;
    while (r < R_ && co[r + 1] <= b) ++r;
    if (r >= R_) return;                       // uniform: all threads exit together
    const int base = ro[r] + (b - co[r]) * SC_T;
    const int nt = min(SC_T, ro[r + 1] - base);
    if (t < SC_T) eids[t] = (t < nt) ? eidx[base + t] : -1;
    __syncthreads();
    {   // stage zh/zt: 256 float4, 1 per thread
        int tt = t >> 5, c4 = t & 31;
        float4 vh = make_float4(0.f, 0.f, 0.f, 0.f), vt = vh;
        int e = eids[tt];
        if (e >= 0) {
            vh = ((const float4*)(z + (size_t)head[e] * TD))[c4];
            vt = ((const float4*)(z + (size_t)tail[e] * TD))[c4];
        }
        ((float4*)(zhL + tt * TD))[c4] = vh;
        ((float4*)(ztL + tt * TD))[c4] = vt;
    }
    {   // stage W[r]: 4096 float4
        const float4* W4 = (const float4*)(relW + (size_t)r * TD * TD);
        float4* Wl4 = (float4*)Wl;
#pragma unroll
        for (int i = 0; i < 16; ++i) Wl4[t + i * 256] = W4[t + i * 256];
    }
    __syncthreads();

    const int c  = (t & 31) * 4;    // cols c..c+3
    const int i0 = (t >> 5) * 16;   // 16-row i segment
    float4 acc[SC_T];
#pragma unroll
    for (int u = 0; u < SC_T; ++u) acc[u] = make_float4(0.f, 0.f, 0.f, 0.f);
#pragma unroll 4
    for (int i = i0; i < i0 + 16; ++i) {
        float4 wv = *(const float4*)&Wl[i * TD + c];
#pragma unroll
        for (int u = 0; u < SC_T; ++u) {
            float h = zhL[u * TD + i];
            acc[u].x = fmaf(h, wv.x, acc[u].x);
            acc[u].y = fmaf(h, wv.y, acc[u].y);
            acc[u].z = fmaf(h, wv.z, acc[u].z);
            acc[u].w = fmaf(h, wv.w, acc[u].w);
        }
    }
    float pth[SC_T];
#pragma unroll
    for (int u = 0; u < SC_T; ++u) {
        float4 z4 = *(const float4*)&ztL[u * TD + c];
        pth[u] = acc[u].x * z4.x + acc[u].y * z4.y + acc[u].z * z4.z + acc[u].w * z4.w;
    }
#pragma unroll
    for (int off = 32; off > 0; off >>= 1)
#pragma unroll
        for (int u = 0; u < SC_T; ++u) pth[u] += __shfl_down(pth[u], off);
    if ((t & 63) == 0) {
        int wv = t >> 6;
#pragma unroll
        for (int u = 0; u < SC_T; ++u) red[wv][u] = pth[u];
    }
    __syncthreads();
    if (t < SC_T) {
        int e = eids[t];
        if (e >= 0) out[e] = red[0][t] + red[1][t] + red[2][t] + red[3][t];
    }
}

extern "C" void kernel_launch(void* const* d_in, const int* in_sizes, int n_in,
                              void* d_out, int out_size, void* d_ws, size_t ws_size,
                              hipStream_t stream) {
    const float* x0   = (const float*)d_in[0];
    const float* W1   = (const float*)d_in[1];
    const float* b1   = (const float*)d_in[2];
    const float* W2   = (const float*)d_in[3];
    const float* b2   = (const float*)d_in[4];
    const float* relW = (const float*)d_in[5];
    const int*   ei   = (const int*)d_in[6];
    const int*   rel  = (const int*)d_in[7];
    const int*   head = (const int*)d_in[8];
    const int*   tail = (const int*)d_in[9];
    float* outp = (float*)d_out;

    const int N_  = in_sizes[0] / TD;
    const int E_  = in_sizes[6] / 2;
    const int ES_ = in_sizes[7];
    const int R_  = in_sizes[5] / (TD * TD);
    const int ntiles64 = (N_ + 63) / 64;
    const int NB    = (N_ + (1 << BKT_SH) - 1) >> BKT_SH;   // <= 1024 for N <= 131072
    const int chunk = (E_ + NBLK - 1) / NBLK;

    char* p = (char*)d_ws;
    auto alloc = [&](size_t bytes) { char* r = p; p += (bytes + 255) & ~(size_t)255; return r; };
    float*          dinv   = (float*)         alloc((size_t)N_ * 4);
    int*            rowptr = (int*)           alloc(((size_t)N_ + 1) * 4);
    int*            bh     = (int*)           alloc((size_t)NB * NBLK * 4);
    int*            tot    = (int*)           alloc((size_t)NB * 4);
    int*            boff   = (int*)           alloc(((size_t)NB + 1) * 4);
    int*            esrc   = (int*)           alloc((size_t)E_ * 4);
    unsigned short* Wt     = (unsigned short*)alloc((size_t)4 * 16384 * 2);   // W1h,W1l,W2h,W2l
    int*            rcount = (int*)           alloc((size_t)R_ * 4);
    int*            roff   = (int*)           alloc(((size_t)R_ + 1) * 4);
    int*            chkoff = (int*)           alloc(((size_t)R_ + 1) * 4);
    int*            cursor = (int*)           alloc((size_t)R_ * 4);
    int*            eidx   = (int*)           alloc((size_t)ES_ * 4);
    unsigned short* bufA   = (unsigned short*)alloc((size_t)N_ * TD * 2);     // bf16 h-scaled
    float*          bufB   = (float*)         alloc((size_t)N_ * TD * 4);     // f32 conv out
    int*            ebuf   = (int*)bufA;   // alias: dead before first k_gemm writes bufA (E*4 <= N*TD*2)

    hipMemsetAsync(rcount, 0, (size_t)R_ * 4, stream);

    // atomic-free CSR: hist -> scanA -> scanB -> scatter -> per-bucket build (rowptr/dinv/esrc)
    kc_hist <<<NBLK, 256, 0, stream>>>(ei, bh, E_, NB, chunk);
    kc_scanA<<<NB, 64, 0, stream>>>(bh, tot, NB);
    kc_scanB<<<1, 256, 0, stream>>>(tot, boff, NB, rowptr + N_);
    kc_scat <<<NBLK, 256, 0, stream>>>(ei, bh, boff, ebuf, E_, NB, chunk);
    kc_build<<<NB, 256, 0, stream>>>(ebuf, boff, rowptr, dinv, esrc, N_);

    k_wsplit<<<128, 256, 0, stream>>>(W1, W2, Wt);

    // relation bucketing for scoring (block-aggregated atomics)
    k_rcnt  <<<(ES_ + 1023) / 1024, 256, 0, stream>>>(rel, rcount, ES_);
    k_roff  <<<1, 64, 0, stream>>>(rcount, roff, chkoff, R_);
    hipMemcpyAsync(cursor, roff, (size_t)R_ * 4, hipMemcpyDeviceToDevice, stream);
    k_bucket<<<(ES_ + 1023) / 1024, 256, 0, stream>>>(rel, cursor, eidx, ES_);

    // conv1: bufA = bf16(dinv * (x0 @ W1)); bufB = relu(dinv*agg(bufA) + b1)
    k_gemm<<<ntiles64, 256, 0, stream>>>(x0, Wt, Wt + 16384, dinv, bufA, N_);
    k_agg <<<(N_ + 15) / 16, 256, 0, stream>>>(bufA, rowptr, esrc, dinv, b1, bufB, N_, 1);
    // conv2: bufA = bf16(dinv * (bufB @ W2)); bufB = dinv*agg(bufA) + b2  (= z)
    k_gemm<<<ntiles64, 256, 0, stream>>>(bufB, Wt + 32768, Wt + 49152, dinv, bufA, N_);
    k_agg <<<(N_ + 15) / 16, 256, 0, stream>>>(bufA, rowptr, esrc, dinv, b2, bufB, N_, 0);

    // scoring: blocks = chunks (upper bound ES/SC_T + R); out-of-range blocks exit via chunkoff
    k_score_r<<<(ES_ + SC_T - 1) / SC_T + R_, 256, 0, stream>>>(bufB, relW, eidx, head, tail,
                                                                roff, chkoff, outp, R_);
}